// Round 9
// baseline (3819.788 us; speedup 1.0000x reference)
//
#include <hip/hip_runtime.h>

// RNN scan v7 — verified-XCD-local exchange with safe LLC fallback.
// 64 blocks = 8 groups(batch 16) x 8 slices(64 hidden cols); 5 waves: 4 compute + 1 poller.
// Startup probe: plain-store token + sc0-load poll among the 8 group members tests L2
// coherence end-to-end; consensus via sc0sc1. FAST: all exchange plain/sc0 (shared L2).
// SLOW: all sc0sc1 (v6b-proven). Sentinel-in-data, 4 slots mod 4, poller wave mirrors
// slot into LDS + mbox release. Compute: one vmcnt(0)/step (old stores + aged prefetch),
// post-spin prefetch (parity-unrolled reg dbuf), merged rec+readout MFMA loop.

#define TSTEPS 1024
#define HDIM   512
#define IDIM   64
#define ODIM   64
#define NSCALE 0.035355339059327376f  /* sqrt(0.5)*0.05 */
#define SENTI  ((int)0x7F7F7F7F)

typedef short bf16x8  __attribute__((ext_vector_type(8)));
typedef float f32x4   __attribute__((ext_vector_type(4)));
typedef int   int4v   __attribute__((ext_vector_type(4)));
typedef int   int2v   __attribute__((ext_vector_type(2)));

template<bool B> struct BC { static constexpr bool v = B; };
template<int I>  struct IC { static constexpr int  v = I; };

__device__ __forceinline__ unsigned short f2bf(float f){
  unsigned u = __float_as_uint(f);
  u = (u + 0x7fffu + ((u >> 16) & 1u)) >> 16;  // RN-even; inputs never NaN
  return (unsigned short)u;
}
__device__ __forceinline__ float tanh_fast(float x){
  float e = __expf(2.0f * x);
  return 1.0f - 2.0f / (e + 1.0f);
}
template<bool FAST>
__device__ __forceinline__ void ex_store8(void* p, int2v v){
  if constexpr (FAST)
    asm volatile("global_store_dwordx2 %0, %1, off" :: "v"(p), "v"(v) : "memory");
  else
    asm volatile("global_store_dwordx2 %0, %1, off sc0 sc1" :: "v"(p), "v"(v) : "memory");
}
__device__ __forceinline__ void st_plain4(unsigned* p, unsigned v){
  asm volatile("global_store_dword %0, %1, off" :: "v"(p), "v"(v) : "memory");
}
__device__ __forceinline__ void st_llc4(unsigned* p, unsigned v){
  asm volatile("global_store_dword %0, %1, off sc0 sc1" :: "v"(p), "v"(v) : "memory");
}
__device__ __forceinline__ unsigned ld_sc0(const unsigned* p){
  unsigned r;
  asm volatile("global_load_dword %0, %1, off sc0\n\ts_waitcnt vmcnt(0)"
               : "=v"(r) : "v"(p) : "memory");
  return r;
}
__device__ __forceinline__ unsigned ld_llc(const unsigned* p){
  unsigned r;
  asm volatile("global_load_dword %0, %1, off sc0 sc1\n\ts_waitcnt vmcnt(0)"
               : "=v"(r) : "v"(p) : "memory");
  return r;
}

// ---- phase 1: weight conversion / transposes (bf16) ----
__global__ void prep_kernel(const float* __restrict__ wi, const float* __restrict__ wrec,
                            const float* __restrict__ wo,
                            unsigned short* __restrict__ wrecb,
                            unsigned short* __restrict__ wiT,
                            unsigned short* __restrict__ woT){
  int i = blockIdx.x * 256 + threadIdx.x;
  if (i < HDIM*HDIM){
    wrecb[i] = f2bf(wrec[i]);                       // [j][k]
  } else if (i < HDIM*HDIM + HDIM*IDIM){
    int q = i - HDIM*HDIM; int j = q >> 6, ii = q & 63;
    wiT[q] = f2bf(wi[ii*HDIM + j]);                 // wiT[j][i]
  } else if (i < HDIM*HDIM + HDIM*IDIM + ODIM*HDIM){
    int q = i - HDIM*HDIM - HDIM*IDIM; int o = q >> 9, k = q & 511;
    woT[q] = f2bf(wo[k*ODIM + o]);                  // woT[o][k]
  }
}

// ---- phase 2: sequential scan ----
__global__ __launch_bounds__(320, 1) void rnn_scan(
    const float* __restrict__ input, const float* __restrict__ noise,
    const float* __restrict__ brec,  const float* __restrict__ h0,
    const unsigned short* __restrict__ wrecb,
    const unsigned short* __restrict__ wiT,
    const unsigned short* __restrict__ woT,
    unsigned short* __restrict__ tanhbuf,   // [4 slot][8 group][16KB frag-ordered]
    unsigned int*  __restrict__ probe,      // [64] stride-16 token words
    unsigned int*  __restrict__ verdict,    // [64] stride-16 verdict words
    float* __restrict__ out)
{
  __shared__ __align__(16) short lds_tanh[32768];  // 64KB: 4-deep mirror of group slot
  __shared__ int mbox0;
  __shared__ int fast_s;

  const int tid = threadIdx.x, bid = blockIdx.x;
  const int g = bid & 7, s = bid >> 3;
  const int l = tid & 63, w = tid >> 6;            // waves 0-3 compute, 4 poller
  const int lr = l & 15, kg = l >> 4, b0 = g * 16;
  const bool ro_on = (s < 4);
  const int TL = ro_on ? TSTEPS : TSTEPS - 1;
  char* const tbb = (char*)tanhbuf;
  const f32x4 zero4 = {0.f, 0.f, 0.f, 0.f};

  if (tid == 0){ mbox0 = 0; fast_s = 0; }

  // ---- weight residency (overlaps handshake) ----
  const int jrow = s*64 + w*16 + lr;
  bf16x8 Arec[16]; bf16x8 Awi0{}, Awi1{}; bf16x8 Awo[16] = {};
  const int j0 = s*64 + w*16 + 4*kg;
  f32x4 brec4 = zero4; float h[4] = {0.f,0.f,0.f,0.f};
  const float* nbase = noise + ((long)(b0 + lr))*TSTEPS*HDIM + j0;
  const float* irow  = input + ((long)(b0 + lr))*TSTEPS*IDIM;
  const int pub_off = s*2048 + (w>>1)*1024
                    + (lr + 16*((w&1)*2 + (kg>>1)))*16 + (kg&1)*8;
  if (w < 4){
#pragma unroll
    for (int kt = 0; kt < 16; ++kt)
      Arec[kt] = *(const bf16x8*)(wrecb + jrow*HDIM + kt*32 + kg*8);
    Awi0 = *(const bf16x8*)(wiT + jrow*IDIM +  0 + kg*8);
    Awi1 = *(const bf16x8*)(wiT + jrow*IDIM + 32 + kg*8);
    if (ro_on){
      const int ocol = s*16 + lr;
#pragma unroll
      for (int ci = 0; ci < 16; ++ci)
        Awo[ci] = *(const bf16x8*)(woT + ocol*HDIM + ci*32 + kg*8);
    }
    brec4 = *(const f32x4*)(brec + j0);
    f32x4 h04 = *(const f32x4*)(h0 + j0);
#pragma unroll
    for (int r = 0; r < 4; ++r) h[r] = h04[r];
  }

  // ---- startup handshake: does plain-store -> sc0-load work across the group? ----
  if (w == 0){
    if (l == 0) st_plain4(probe + bid*16, 1u);
    unsigned ok = 1;
    if (l < 8){
      const unsigned* pp = probe + (g + 8*l)*16;
      int seen = 0;
      for (int it = 0; it < 600 && !seen; ++it) seen = (ld_sc0(pp) != 0);
      ok = (unsigned)seen;
    }
    ok = __all((l < 8) ? (int)ok : 1) ? 1u : 0u;
    if (l == 0) st_llc4(verdict + bid*16, ok + 1u);      // 1=slow vote, 2=fast vote
    unsigned af = 1;
    if (l < 8){
      const unsigned* vp = verdict + (g + 8*l)*16;
      unsigned v; do { v = ld_llc(vp); } while (v == 0); // reliable: all blocks store
      af = (v == 2u);
    }
    af = __all((l < 8) ? (int)af : 1) ? 1u : 0u;
    if (l == 0) fast_s = (int)af;
  }
  __syncthreads();
  const bool FASTRUN = (fast_s != 0);

  auto run = [&](auto fc){
    constexpr bool FAST = decltype(fc)::v;
    if (w < 4){
      // ================= compute waves =================
      auto pack8 = [&](float4 a, float4 b) -> bf16x8 {
        bf16x8 r;
        r[0]=(short)f2bf(a.x); r[1]=(short)f2bf(a.y); r[2]=(short)f2bf(a.z); r[3]=(short)f2bf(a.w);
        r[4]=(short)f2bf(b.x); r[5]=(short)f2bf(b.y); r[6]=(short)f2bf(b.z); r[7]=(short)f2bf(b.w);
        return r;
      };
      // prologue: publish tanh(h0) into slot 0; load t=0 noise/input
      {
        int2v pv;
        pv.x = (int)((unsigned)f2bf(tanh_fast(h[0])) | ((unsigned)f2bf(tanh_fast(h[1])) << 16));
        pv.y = (int)((unsigned)f2bf(tanh_fast(h[2])) | ((unsigned)f2bf(tanh_fast(h[3])) << 16));
        ex_store8<FAST>(tbb + g*16384 + pub_off, pv);
      }
      f32x4  nz[2]; float4 fi[2][4];
      nz[0] = *(const f32x4*)nbase;
      fi[0][0] = *(const float4*)(irow + 8*kg);
      fi[0][1] = *(const float4*)(irow + 8*kg + 4);
      fi[0][2] = *(const float4*)(irow + 32 + 8*kg);
      fi[0][3] = *(const float4*)(irow + 32 + 8*kg + 4);
      nz[1] = zero4; fi[1][0]=fi[0][0]; fi[1][1]=fi[0][1]; fi[1][2]=fi[0][2]; fi[1][3]=fi[0][3];

      auto step = [&](int t, auto pc){
        constexpr int P = decltype(pc)::v;
        const bool comp = (t < TSTEPS);
        asm volatile("s_waitcnt vmcnt(0)" ::: "memory");   // old stores + aged prefetch: ~free
        while (*(volatile int*)&mbox0 < t + 1) {}          // poller release
        __builtin_amdgcn_sched_barrier(0);
        if (t + 1 < TSTEPS){                               // prefetch t+1 (ages a full iter)
          const float* ip = irow + (t + 1)*IDIM;
          fi[1-P][0] = *(const float4*)(ip + 8*kg);
          fi[1-P][1] = *(const float4*)(ip + 8*kg + 4);
          fi[1-P][2] = *(const float4*)(ip + 32 + 8*kg);
          fi[1-P][3] = *(const float4*)(ip + 32 + 8*kg + 4);
          nz[1-P]    = *(const f32x4*)(nbase + (long)(t + 1)*HDIM);
        }
        if (t >= 1 && comp){                               // sentinel-clear slot t-1
          int2v sv; sv.x = SENTI; sv.y = SENTI;
          ex_store8<FAST>(tbb + (((t + 3)&3)*8 + g)*16384 + pub_off, sv);
        }
        f32x4 ac0 = zero4, ac1 = zero4, ac2 = zero4, ac3 = zero4, ro = zero4;
        if (comp){
          ac0 = __builtin_amdgcn_mfma_f32_16x16x32_bf16(Awi0, pack8(fi[P][0], fi[P][1]), zero4, 0,0,0);
          ac0 = __builtin_amdgcn_mfma_f32_16x16x32_bf16(Awi1, pack8(fi[P][2], fi[P][3]), ac0, 0,0,0);
        }
        const bool rdo = (t >= 1) && ro_on;
        const char* lb = (const char*)lds_tanh + (t&3)*16384 + l*16;
#pragma unroll
        for (int kt = 0; kt < 16; ++kt){
          bf16x8 qk = *(const bf16x8*)(lb + kt*1024);
          if (comp){
            if      ((kt&3)==0) ac0 = __builtin_amdgcn_mfma_f32_16x16x32_bf16(Arec[kt], qk, ac0, 0,0,0);
            else if ((kt&3)==1) ac1 = __builtin_amdgcn_mfma_f32_16x16x32_bf16(Arec[kt], qk, ac1, 0,0,0);
            else if ((kt&3)==2) ac2 = __builtin_amdgcn_mfma_f32_16x16x32_bf16(Arec[kt], qk, ac2, 0,0,0);
            else                ac3 = __builtin_amdgcn_mfma_f32_16x16x32_bf16(Arec[kt], qk, ac3, 0,0,0);
          }
          if (rdo) ro = __builtin_amdgcn_mfma_f32_16x16x32_bf16(Awo[kt], qk, ro, 0,0,0);
        }
        if (comp){
          float tb[4];
#pragma unroll
          for (int r = 0; r < 4; ++r){
            float rec = ac0[r] + ac1[r] + ac2[r] + ac3[r] + brec4[r];
            float hn  = 0.5f*h[r] + 0.5f*rec + NSCALE*nz[P][r];
            h[r] = hn;
            tb[r] = tanh_fast(hn);
          }
          int2v pv;
          pv.x = (int)((unsigned)f2bf(tb[0]) | ((unsigned)f2bf(tb[1]) << 16));
          pv.y = (int)((unsigned)f2bf(tb[2]) | ((unsigned)f2bf(tb[3]) << 16));
          ex_store8<FAST>(tbb + (((t + 1)&3)*8 + g)*16384 + pub_off, pv);  // fire-and-forget
        }
        if (rdo && (lr >> 2) == w)
          *(f32x4*)(out + (((long)(b0 + lr))*TSTEPS + (t - 1))*ODIM + s*16 + 4*kg) = ro;
      };

      for (int t = 0; t <= TL; t += 2){
        step(t, IC<0>{});
        if (t + 1 <= TL) step(t + 1, IC<1>{});
      }
    } else {
      // ================= poller wave (wave 4): 16 chunks =================
      for (int u = 0; u <= TL; ++u){
        const char* p0 = tbb + ((u&3)*8 + g)*16384 + l*16;
        const char* p1 = p0 + 4096; const char* p2 = p0 + 8192; const char* p3 = p0 + 12288;
        char* lb = (char*)lds_tanh + (u&3)*16384 + l*16;
        int4v c0,c1,c2,c3,c4,c5,c6,c7,c8,c9,c10,c11,c12,c13,c14,c15;
#define PISS(CV, B, IMM) do{ if constexpr (FAST) { \
          asm volatile("global_load_dwordx4 %0, %1, off offset:" #IMM " sc0" \
                       : "=v"(CV) : "v"(B) : "memory"); \
        } else { \
          asm volatile("global_load_dwordx4 %0, %1, off offset:" #IMM " sc0 sc1" \
                       : "=v"(CV) : "v"(B) : "memory"); } }while(0)
        PISS(c0,p0,0); PISS(c1,p0,1024); PISS(c2,p0,2048); PISS(c3,p0,3072);
        PISS(c4,p1,0); PISS(c5,p1,1024); PISS(c6,p1,2048); PISS(c7,p1,3072);
        PISS(c8,p2,0); PISS(c9,p2,1024); PISS(c10,p2,2048); PISS(c11,p2,3072);
        PISS(c12,p3,0); PISS(c13,p3,1024); PISS(c14,p3,2048); PISS(c15,p3,3072);
        unsigned pend = 0xFFFFu;
        for (;;){
          asm volatile("s_waitcnt vmcnt(0)" ::: "memory");
          __builtin_amdgcn_sched_barrier(0);
          unsigned np = 0;
#define PCH(J, CV) if (pend & (1u<<J)){ \
            int bad = (CV[0]==SENTI)|(CV[1]==SENTI)|(CV[2]==SENTI)|(CV[3]==SENTI); \
            if (__any(bad)) np |= (1u<<J); else *(int4v*)(lb + J*1024) = CV; }
          PCH(0,c0)  PCH(1,c1)  PCH(2,c2)  PCH(3,c3)
          PCH(4,c4)  PCH(5,c5)  PCH(6,c6)  PCH(7,c7)
          PCH(8,c8)  PCH(9,c9)  PCH(10,c10) PCH(11,c11)
          PCH(12,c12) PCH(13,c13) PCH(14,c14) PCH(15,c15)
#undef PCH
          if (!np) break;
#define PRL(J, CV, B, IMM) if (np & (1u<<J)) PISS(CV, B, IMM);
          PRL(0,c0,p0,0) PRL(1,c1,p0,1024) PRL(2,c2,p0,2048) PRL(3,c3,p0,3072)
          PRL(4,c4,p1,0) PRL(5,c5,p1,1024) PRL(6,c6,p1,2048) PRL(7,c7,p1,3072)
          PRL(8,c8,p2,0) PRL(9,c9,p2,1024) PRL(10,c10,p2,2048) PRL(11,c11,p2,3072)
          PRL(12,c12,p3,0) PRL(13,c13,p3,1024) PRL(14,c14,p3,2048) PRL(15,c15,p3,3072)
#undef PRL
          pend = np;
        }
#undef PISS
        asm volatile("s_waitcnt lgkmcnt(0)" ::: "memory");  // mirror visible
        *(volatile int*)&mbox0 = u + 1;                     // release
      }
    }
  };

  if (FASTRUN) run(BC<true>{});
  else         run(BC<false>{});
}

extern "C" void kernel_launch(void* const* d_in, const int* in_sizes, int n_in,
                              void* d_out, int out_size, void* d_ws, size_t ws_size,
                              hipStream_t stream){
  (void)in_sizes; (void)n_in; (void)ws_size; (void)out_size;
  const float* input = (const float*)d_in[0];
  const float* wi    = (const float*)d_in[1];
  const float* wrec  = (const float*)d_in[2];
  const float* wo    = (const float*)d_in[3];
  const float* brec  = (const float*)d_in[4];
  const float* h0    = (const float*)d_in[5];
  const float* noise = (const float*)d_in[6];
  float* out = (float*)d_out;

  char* ws = (char*)d_ws;
  unsigned short* wrecb = (unsigned short*)(ws);            // 512KB
  unsigned short* wiT   = (unsigned short*)(ws + 524288);   // 64KB
  unsigned short* woT   = (unsigned short*)(ws + 589824);   // 64KB
  unsigned short* tanhb = (unsigned short*)(ws + 655360);   // 512KB: 4 slots x 8 grp x 16KB
  unsigned int*   probe = (unsigned int*)  (ws + 1179648);  // 4KB tokens
  unsigned int*   verd  = (unsigned int*)  (ws + 1183744);  // 4KB verdicts

  hipMemsetAsync(ws + 655360, 0x7F, 524288, stream);        // sentinel-fill all slots
  hipMemsetAsync(ws + 1179648, 0, 8192, stream);            // clear probe/verdict
  prep_kernel<<<1280, 256, 0, stream>>>(wi, wrec, wo, wrecb, wiT, woT);
  rnn_scan<<<64, 320, 0, stream>>>(input, noise, brec, h0, wrecb, wiT, woT,
                                   tanhb, probe, verd, out);
}